// Round 9
// baseline (378.081 us; speedup 1.0000x reference)
//
#include <hip/hip_runtime.h>

// sparsemax over axis=2 of x[8][16][4096][64] (fp32) — 3-kernel, contiguous reads.
//
// R7 evidence: tau pass alone = 96us @ 1.4 TB/s read-only. Old tile read 64B
// per row at 256B stride -> each wave load = 16 scattered cache lines ->
// miss-queue entry per 64B -> latency-bound ~1.4 TB/s.
// Fix: block = (slab, 1024 contiguous rows x all 64 cols) = 256KB contiguous;
// lane map (sub=l>>4, d4=l&15) -> each wave load = 64 consecutive float4
// (1KB burst) == m13's 6.3 TB/s pattern.
//
// R9 vs R8 (never ran): fixed divergent __syncthreads in trim-flush (hoisted
// out of conditional); LCAP 128->192 (expected candidates/quarter-col ~108,
// sigma~10 -> 128 overflowed often, 192 is 8-sigma safe). LDS 54KB -> 2 blk/CU.
//
// K1: contiguous stream, per-wave col-max (xor16/32 butterfly), extract
//     candidates immediately w/ wave-max-1 threshold (superset; extras are
//     filtered by Newton's z>tau since tau>=-1 in shifted domain), block-max
//     trim on flush -> d_ws lists (cap 64) + per-quarter partial maxes.
// K2: per column: gmax = max of 4 partials; Newton-from-below on merged lists
//     in shifted domain z = v - gmax (exact; absmax 0.0 in R6/R7). Any
//     overflow -> strided re-read fallback (correct, never taken for Gaussian).
// K3: grid-stride apply out = relu((x - gmax) - tau)  (R7-proven).
//
// ws (8.72 MB): pmax f[8192*4] | gcnt i[8192*4] | glist f[8192*4*64]
//               | gmax f[8192] | tau f[8192].  Too small -> R6 fused fallback.

#define LCAP 192   // per-wave-threshold LDS list cap
#define GCAP 64    // trimmed (block-max-1) global list cap

typedef float f32x4 __attribute__((ext_vector_type(4)));

// ---------------------------------------------------------------- K1 ----
__global__ __launch_bounds__(1024)
void k1_maxextract(const float* __restrict__ x,
                   float* __restrict__ pmax,    // [8192][4]
                   int*   __restrict__ gcnt,    // [8192][4]
                   float* __restrict__ glist)   // [8192][4][GCAP]
{
    const int b  = blockIdx.x;      // 0..511
    const int bh = b >> 2;          // slab
    const int q  = b & 3;           // quarter (1024 rows)

    const int t   = threadIdx.x;    // 0..1023
    const int l   = t & 63;
    const int wv  = t >> 6;         // 0..15
    const int sub = l >> 4;         // row within 4-row group
    const int d4  = l & 15;         // float4 column

    __shared__ float list[64][LCAP];
    __shared__ int   cnt[64];
    __shared__ int   cnt2[64];
    __shared__ float redbuf[16][64];
    __shared__ float bmaxs[64];

    const f32x4* __restrict__ x4 = reinterpret_cast<const f32x4*>(x);
    // f4 index: bh*65536 + row*16 + d4 ; row = q*1024 + wv*64 + s*4 + sub
    const size_t base = (size_t)bh * 65536 + (size_t)q * 16384
                      + (size_t)wv * 1024 + (size_t)l;

    if (t < 64) { cnt[t] = 0; cnt2[t] = 0; }
    __syncthreads();

    // ---- contiguous load: each wave inst = 64 consecutive f4 (1KB burst) ----
    f32x4 c[16];
#pragma unroll
    for (int s = 0; s < 16; ++s)
        c[s] = x4[base + (size_t)s * 64];

    // ---- per-thread max over its 16 rows (cols 4*d4..+3) ----
    f32x4 m = c[0];
#pragma unroll
    for (int s = 1; s < 16; ++s) {
        m.x = fmaxf(m.x, c[s].x);
        m.y = fmaxf(m.y, c[s].y);
        m.z = fmaxf(m.z, c[s].z);
        m.w = fmaxf(m.w, c[s].w);
    }
    // ---- wave max per col: xor 16,32 keeps d4 class ----
#pragma unroll
    for (int mask = 16; mask <= 32; mask <<= 1) {
        m.x = fmaxf(m.x, __shfl_xor(m.x, mask));
        m.y = fmaxf(m.y, __shfl_xor(m.y, mask));
        m.z = fmaxf(m.z, __shfl_xor(m.z, mask));
        m.w = fmaxf(m.w, __shfl_xor(m.w, mask));
    }
    if (sub == 0) {                  // one lane per d4 class
        redbuf[wv][d4 * 4 + 0] = m.x;
        redbuf[wv][d4 * 4 + 1] = m.y;
        redbuf[wv][d4 * 4 + 2] = m.z;
        redbuf[wv][d4 * 4 + 3] = m.w;
    }

    // ---- extract NOW with wave-local threshold (superset of final support;
    //      v <= gmax-1 gives z <= -1 which Newton's z>tau never accepts) ----
    const float Tx = m.x - 1.0f, Ty = m.y - 1.0f, Tz = m.z - 1.0f, Tw = m.w - 1.0f;
    const int c0 = d4 * 4;
#pragma unroll
    for (int s = 0; s < 16; ++s) {
        if (c[s].x > Tx) { int p = atomicAdd(&cnt[c0+0], 1); if (p < LCAP) list[c0+0][p] = c[s].x; }
        if (c[s].y > Ty) { int p = atomicAdd(&cnt[c0+1], 1); if (p < LCAP) list[c0+1][p] = c[s].y; }
        if (c[s].z > Tz) { int p = atomicAdd(&cnt[c0+2], 1); if (p < LCAP) list[c0+2][p] = c[s].z; }
        if (c[s].w > Tw) { int p = atomicAdd(&cnt[c0+3], 1); if (p < LCAP) list[c0+3][p] = c[s].w; }
    }
    __syncthreads();

    // ---- block (quarter) max per col ----
    if (t < 64) {
        float g = redbuf[0][t];
#pragma unroll
        for (int w = 1; w < 16; ++w) g = fmaxf(g, redbuf[w][t]);
        bmaxs[t] = g;
        pmax[((size_t)bh * 64 + t) * 4 + q] = g;
    }
    __syncthreads();

    // ---- trim-flush: keep v > quartermax-1; wave wv owns cols wv*4..wv*4+3.
    //      Barrier is UNCONDITIONAL (R8 had it inside the else -> UB). ----
    {
        const int j   = l >> 4;          // 0..3
        const int g16 = l & 15;          // lane within col group
        const int d   = wv * 4 + j;
        const int n   = cnt[d];
        const size_t gbase = (((size_t)bh * 64 + d) * 4 + q) * GCAP;
        const float T = bmaxs[d] - 1.0f;
        if (n <= LCAP) {
            for (int p = g16; p < n; p += 16) {
                float v = list[d][p];
                if (v > T) {
                    int i = atomicAdd(&cnt2[d], 1);
                    if (i < GCAP) glist[gbase + i] = v;
                }
            }
        }
        __syncthreads();                 // all threads, unconditional
        if (g16 == 0) {
            // raw cnt2 may exceed GCAP (stores dropped) -> K2's >GCAP check
            // routes to fallback; LCAP overflow -> explicit sentinel.
            gcnt[((size_t)bh * 64 + d) * 4 + q] =
                (n > LCAP) ? (GCAP + 1000) : cnt2[d];
        }
    }
}

// ---------------------------------------------------------------- K2 ----
__global__ __launch_bounds__(256)
void k2_newton(const float* __restrict__ x,
               const float* __restrict__ pmax,
               const int*   __restrict__ gcnt,
               const float* __restrict__ glist,
               float* __restrict__ gmaxo,
               float* __restrict__ tauo)
{
    const int col = blockIdx.x * 4 + (threadIdx.x >> 6);   // 0..8191
    const int l   = threadIdx.x & 63;

    const float g = fmaxf(fmaxf(pmax[col*4+0], pmax[col*4+1]),
                          fmaxf(pmax[col*4+2], pmax[col*4+3]));
    int cs[4];
#pragma unroll
    for (int q = 0; q < 4; ++q) cs[q] = gcnt[col*4+q];
    const bool ovf = (cs[0] > GCAP) | (cs[1] > GCAP) | (cs[2] > GCAP) | (cs[3] > GCAP);

    float tau = -1.0f;
    if (!ovf) {
        const float* __restrict__ L = glist + (size_t)col * 4 * GCAP;
        for (int it = 0; it < 64; ++it) {
            float sv = 0.f, cc = 0.f;
#pragma unroll
            for (int q = 0; q < 4; ++q) {
                for (int p = l; p < cs[q]; p += 64) {
                    float z = L[q * GCAP + p] - g;     // same rounding as reference
                    if (z > tau) { sv += z; cc += 1.f; }
                }
            }
#pragma unroll
            for (int mask = 1; mask <= 32; mask <<= 1) {
                sv += __shfl_xor(sv, mask);
                cc += __shfl_xor(cc, mask);
            }
            if (cc < 0.5f) break;
            float tn = (sv - 1.0f) / cc;
            tn = fmaxf(tn, tau);
            if (tn == tau) break;                       // exact fixed point
            tau = tn;
        }
    } else {
        // correctness fallback (never taken for Gaussian): strided column read
        const float* vb = x + (size_t)(col >> 6) * 262144 + (col & 63);
        for (int it = 0; it < 64; ++it) {
            float sv = 0.f, cc = 0.f;
            for (int p = l; p < 4096; p += 64) {
                float z = vb[(size_t)p * 64] - g;
                if (z > tau) { sv += z; cc += 1.f; }
            }
#pragma unroll
            for (int mask = 1; mask <= 32; mask <<= 1) {
                sv += __shfl_xor(sv, mask);
                cc += __shfl_xor(cc, mask);
            }
            if (cc < 0.5f) break;
            float tn = (sv - 1.0f) / cc;
            tn = fmaxf(tn, tau);
            if (tn == tau) break;
            tau = tn;
        }
    }
    if (l == 0) { gmaxo[col] = g; tauo[col] = tau; }
}

// ---------------------------------------------------------------- K3 ----
__global__ __launch_bounds__(256)
void k3_apply(const float* __restrict__ x,
              const float* __restrict__ gmax_in,
              const float* __restrict__ tau_in,
              float* __restrict__ out, int n4)
{
    const f32x4* __restrict__ x4 = reinterpret_cast<const f32x4*>(x);
    const f32x4* __restrict__ g4 = reinterpret_cast<const f32x4*>(gmax_in);
    const f32x4* __restrict__ t4 = reinterpret_cast<const f32x4*>(tau_in);
    f32x4* __restrict__ o4       = reinterpret_cast<f32x4*>(out);

    const int stride = gridDim.x * 256;
    for (int f = blockIdx.x * 256 + threadIdx.x; f < n4; f += stride) {
        const int d4 = f & 15;
        const int bh = f >> 16;
        const int v  = bh * 16 + d4;
        f32x4 xv = x4[f];
        f32x4 g  = g4[v];
        f32x4 tv = t4[v];
        f32x4 o;
        o.x = fmaxf((xv.x - g.x) - tv.x, 0.f);
        o.y = fmaxf((xv.y - g.y) - tv.y, 0.f);
        o.z = fmaxf((xv.z - g.z) - tv.z, 0.f);
        o.w = fmaxf((xv.w - g.w) - tv.w, 0.f);
        o4[f] = o;
    }
}

// ------------------------------------------- fallback: R6 fused (known-good) ----
#define C_CAP 256
__global__ __launch_bounds__(1024, 4)
void sparsemax_fused(const float* __restrict__ x, float* __restrict__ out)
{
    const int b = blockIdx.x, bh = b >> 2, dt = b & 3;
    const int t = threadIdx.x, lane = t & 63, wv = t >> 6, dq = t & 3, iblk = t >> 2;
    __shared__ float list[16][C_CAP];
    __shared__ float redbuf[256];
    __shared__ float gmaxT[16];
    __shared__ float tauLDS[16];
    __shared__ int   cnt[16];
    const f32x4* __restrict__ x4 = reinterpret_cast<const f32x4*>(x);
    f32x4* __restrict__ o4       = reinterpret_cast<f32x4*>(out);
    const size_t slabrow = (size_t)bh * 4096;
    const size_t idx0 = (slabrow + (size_t)iblk) * 16 + (size_t)(dt * 4) + (size_t)dq;
    f32x4 c[16];
#pragma unroll
    for (int s = 0; s < 16; ++s) c[s] = x4[idx0 + (size_t)s * 4096];
    f32x4 m = c[0];
#pragma unroll
    for (int s = 1; s < 16; ++s) {
        m.x = fmaxf(m.x, c[s].x); m.y = fmaxf(m.y, c[s].y);
        m.z = fmaxf(m.z, c[s].z); m.w = fmaxf(m.w, c[s].w);
    }
#pragma unroll
    for (int mask = 4; mask <= 32; mask <<= 1) {
        m.x = fmaxf(m.x, __shfl_xor(m.x, mask));
        m.y = fmaxf(m.y, __shfl_xor(m.y, mask));
        m.z = fmaxf(m.z, __shfl_xor(m.z, mask));
        m.w = fmaxf(m.w, __shfl_xor(m.w, mask));
    }
    if (lane < 4) {
        redbuf[wv*16 + lane*4 + 0] = m.x; redbuf[wv*16 + lane*4 + 1] = m.y;
        redbuf[wv*16 + lane*4 + 2] = m.z; redbuf[wv*16 + lane*4 + 3] = m.w;
    }
    __syncthreads();
    if (t < 16) {
        float g = redbuf[t];
#pragma unroll
        for (int w = 1; w < 16; ++w) g = fmaxf(g, redbuf[w*16 + t]);
        gmaxT[t] = g; cnt[t] = 0;
    }
    __syncthreads();
    const int j0 = dq << 2;
    f32x4 g4v;
    g4v.x = gmaxT[j0+0]; g4v.y = gmaxT[j0+1]; g4v.z = gmaxT[j0+2]; g4v.w = gmaxT[j0+3];
#pragma unroll
    for (int s = 0; s < 16; ++s) {
        float zx = c[s].x - g4v.x, zy = c[s].y - g4v.y, zz = c[s].z - g4v.z, zw = c[s].w - g4v.w;
        if (zx > -1.0f) { int p = atomicAdd(&cnt[j0+0],1); if (p < C_CAP) list[j0+0][p] = zx; }
        if (zy > -1.0f) { int p = atomicAdd(&cnt[j0+1],1); if (p < C_CAP) list[j0+1][p] = zy; }
        if (zz > -1.0f) { int p = atomicAdd(&cnt[j0+2],1); if (p < C_CAP) list[j0+2][p] = zz; }
        if (zw > -1.0f) { int p = atomicAdd(&cnt[j0+3],1); if (p < C_CAP) list[j0+3][p] = zw; }
    }
    __syncthreads();
    {
        const int j = wv; const int n = cnt[j]; float tau = -1.0f;
        if (n <= C_CAP) {
            for (int it = 0; it < 100; ++it) {
                float sv = 0.f, cc = 0.f;
                for (int p = lane; p < n; p += 64) {
                    float v = list[j][p];
                    if (v > tau) { sv += v; cc += 1.f; }
                }
#pragma unroll
                for (int mask = 1; mask <= 32; mask <<= 1) { sv += __shfl_xor(sv, mask); cc += __shfl_xor(cc, mask); }
                if (cc < 0.5f) break;
                float tn = (sv - 1.0f) / cc; tn = fmaxf(tn, tau);
                if (tn == tau) break; tau = tn;
            }
        } else {
            const float g = gmaxT[j];
            const float* vb = x + slabrow * 64 + (size_t)(dt * 16 + j);
            for (int it = 0; it < 100; ++it) {
                float sv = 0.f, cc = 0.f;
                for (int p = lane; p < 4096; p += 64) {
                    float v = vb[(size_t)p * 64] - g;
                    if (v > tau) { sv += v; cc += 1.f; }
                }
#pragma unroll
                for (int mask = 1; mask <= 32; mask <<= 1) { sv += __shfl_xor(sv, mask); cc += __shfl_xor(cc, mask); }
                if (cc < 0.5f) break;
                float tn = (sv - 1.0f) / cc; tn = fmaxf(tn, tau);
                if (tn == tau) break; tau = tn;
            }
        }
        if (lane == 0) tauLDS[j] = tau;
    }
    __syncthreads();
    f32x4 tau4;
    tau4.x = tauLDS[j0+0]; tau4.y = tauLDS[j0+1]; tau4.z = tauLDS[j0+2]; tau4.w = tauLDS[j0+3];
#pragma unroll
    for (int s = 0; s < 16; ++s) {
        f32x4 o;
        o.x = fmaxf((c[s].x - g4v.x) - tau4.x, 0.f);
        o.y = fmaxf((c[s].y - g4v.y) - tau4.y, 0.f);
        o.z = fmaxf((c[s].z - g4v.z) - tau4.z, 0.f);
        o.w = fmaxf((c[s].w - g4v.w) - tau4.w, 0.f);
        o4[idx0 + (size_t)s * 4096] = o;
    }
}

extern "C" void kernel_launch(void* const* d_in, const int* in_sizes, int n_in,
                              void* d_out, int out_size, void* d_ws, size_t ws_size,
                              hipStream_t stream)
{
    (void)n_in; (void)out_size;
    const float* x = (const float*)d_in[0];
    float* out     = (float*)d_out;
    const int total = in_sizes[0];            // 33554432
    const int slabs = total / (4096 * 64);    // 128
    const int ncols = slabs * 64;             // 8192
    const int n4    = total / 4;

    // ws layout
    const size_t off_pmax  = 0;                                   // f[ncols*4]
    const size_t off_gcnt  = off_pmax + (size_t)ncols * 4 * 4;    // i[ncols*4]
    const size_t off_glist = off_gcnt + (size_t)ncols * 4 * 4;    // f[ncols*4*GCAP]
    const size_t off_gmax  = off_glist + (size_t)ncols * 4 * GCAP * 4;
    const size_t off_tau   = off_gmax + (size_t)ncols * 4;
    const size_t ws_need   = off_tau + (size_t)ncols * 4;

    if (ws_size < ws_need) {
        hipLaunchKernelGGL(sparsemax_fused, dim3(slabs * 4), dim3(1024), 0, stream, x, out);
        return;
    }

    char* ws = (char*)d_ws;
    float* pmax  = (float*)(ws + off_pmax);
    int*   gcnt  = (int*)  (ws + off_gcnt);
    float* glist = (float*)(ws + off_glist);
    float* gmax  = (float*)(ws + off_gmax);
    float* tau   = (float*)(ws + off_tau);

    hipLaunchKernelGGL(k1_maxextract, dim3(slabs * 4), dim3(1024), 0, stream,
                       x, pmax, gcnt, glist);
    hipLaunchKernelGGL(k2_newton, dim3(ncols / 4), dim3(256), 0, stream,
                       x, pmax, gcnt, glist, gmax, tau);
    hipLaunchKernelGGL(k3_apply, dim3(2048), dim3(256), 0, stream,
                       x, gmax, tau, out, n4);
}